// Round 1
// baseline (145.341 us; speedup 1.0000x reference)
//
#include <hip/hip_runtime.h>
#include <hip/hip_bf16.h>

typedef __attribute__((ext_vector_type(8))) short bf16x8;
typedef __attribute__((ext_vector_type(4))) float f32x4;

#define LOG2E 1.44269504088896340736f

// ---- workspace layout ----
// bf16 element offsets
#define QB_OFF 2621440
#define KB_OFF 3145728
#define VT_OFF 3670016
#define AO_OFF 4194304
// byte offsets (fp32 tables)
#define T_B   9437184
#define A_B   (T_B + 4096)
#define C_B   (A_B + 20480)
// new: pre-converted bf16 operands (ushort offsets)
#define XB_OFF 8388608              // 3 x [1024][512] bf16 inputs
#define WT_OFF 9961472              // 4 x [512 n][512 k] bf16 transposed weights

struct MegaArgs {
  const float *xq, *xk, *xv, *eg;
  const float *wq, *wk, *wv, *wo;
  const float *bq, *bk, *bv, *bo;
  const float *w1, *b1, *we2, *be2;
  float* out;
  unsigned short* wsb;
  float *wsT, *wsA, *wsC;   // deduped: wsT[0..nu) breakpoints, (int)wsT[512]=nu,
                            // wsA/wsC [h*513 + c] for c in [0, nu]
};

__device__ __forceinline__ unsigned short f2bf(float f) {
  union { __hip_bfloat16 h; unsigned short u; } c;
  c.h = __float2bfloat16(f);
  return c.u;
}

__device__ __forceinline__ uint4 pack8(float4 a, float4 b) {
  union { unsigned short us[8]; uint4 u; } r;
  r.us[0] = f2bf(a.x); r.us[1] = f2bf(a.y); r.us[2] = f2bf(a.z); r.us[3] = f2bf(a.w);
  r.us[4] = f2bf(b.x); r.us[5] = f2bf(b.y); r.us[6] = f2bf(b.z); r.us[7] = f2bf(b.w);
  return r.u;
}

// async 16B global->LDS; LDS dest is wave-uniform base + lane*16 (linear)
__device__ __forceinline__ void gload16(const void* g, void* l) {
  __builtin_amdgcn_global_load_lds(
      (const __attribute__((address_space(1))) unsigned int*)g,
      (__attribute__((address_space(3))) unsigned int*)l, 16, 0, 0);
}

// ---------------- edge-MLP -> exact PWL tables, deduped (1 block, 256 threads) --------
__device__ void prep_block(const MegaArgs& a, char* smem) {
  float* sT   = (float*)smem;                      // 2048
  int*   sIdx = (int*)(smem + 2048);               // 2048 (reused as dedupe totals)
  float (*sDA)[8] = (float (*)[8])(smem + 4096);   // 16384 (rows 0-3 reused as reduce scratch)
  float (*sDC)[8] = (float (*)[8])(smem + 20480);  // 16384
  float* sA0 = (float*)(smem + 36864);             // 32
  float* sC0 = (float*)(smem + 36896);             // 32
  int tid = threadIdx.x, lane = tid & 63, w = tid >> 6;
  float accA[8] = {0,0,0,0,0,0,0,0}, accC[8] = {0,0,0,0,0,0,0,0};
  for (int e = 0; e < 2; ++e) {
    int p = tid + e * 256;
    float ww = a.w1[p], bb = a.b1[p];
    sT[p] = (ww != 0.f) ? (-bb / ww) : -3.4e38f;
    sIdx[p] = p;
#pragma unroll
    for (int h = 0; h < 8; ++h) {
      float w2 = a.we2[p * 8 + h];
      if (ww < 0.f)       { accA[h] += w2 * ww; accC[h] += w2 * bb; }
      else if (ww == 0.f) { accC[h] += w2 * fmaxf(bb, 0.f); }
    }
  }
  __syncthreads();
  for (int size = 2; size <= 512; size <<= 1) {
    for (int stride = size >> 1; stride > 0; stride >>= 1) {
      if (size >= 256 && stride >= 64) __syncthreads();
      else __builtin_amdgcn_wave_barrier();
      int p = tid;
      int i = ((p / stride) * (stride << 1)) + (p % stride);
      int j = i + stride;
      bool up = ((i & size) == 0);
      float ti = sT[i], tj = sT[j];
      if (up ? (ti > tj) : (ti < tj)) {
        sT[i] = tj; sT[j] = ti;
        int t = sIdx[i]; sIdx[i] = sIdx[j]; sIdx[j] = t;
      }
    }
  }
  for (int off = 32; off > 0; off >>= 1) {
#pragma unroll
    for (int h = 0; h < 8; ++h) {
      accA[h] += __shfl_xor(accA[h], off);
      accC[h] += __shfl_xor(accC[h], off);
    }
  }
  if (lane == 0) {
#pragma unroll
    for (int h = 0; h < 8; ++h) { sDA[w][h] = accA[h]; sDC[w][h] = accC[h]; }
  }
  __syncthreads();
  if (tid < 8) {
    sA0[tid] = sDA[0][tid] + sDA[1][tid] + sDA[2][tid] + sDA[3][tid];
    sC0[tid] = sDC[0][tid] + sDC[1][tid] + sDC[2][tid] + sDC[3][tid] + a.be2[tid];
  }
  __syncthreads();
  for (int e = 0; e < 2; ++e) {
    int p = tid + e * 256;
    int k = sIdx[p];
    float wk = a.w1[k], bk2 = a.b1[k];
#pragma unroll
    for (int h = 0; h < 8; ++h) {
      float w2 = a.we2[k * 8 + h];
      float da = 0.f, dc = 0.f;
      if (wk > 0.f)      { da =  w2 * wk; dc =  w2 * bk2; }
      else if (wk < 0.f) { da = -w2 * wk; dc = -w2 * bk2; }
      sDA[p][h] = da; sDC[p][h] = dc;
    }
  }
  __syncthreads();
  for (int off = 1; off < 512; off <<= 1) {
    float ra[2][8], rc[2][8];
#pragma unroll
    for (int e = 0; e < 2; ++e) {
      int p = tid + e * 256;
      if (p >= off) {
#pragma unroll
        for (int h = 0; h < 8; ++h) { ra[e][h] = sDA[p - off][h]; rc[e][h] = sDC[p - off][h]; }
      }
    }
    __syncthreads();
#pragma unroll
    for (int e = 0; e < 2; ++e) {
      int p = tid + e * 256;
      if (p >= off) {
#pragma unroll
        for (int h = 0; h < 8; ++h) { sDA[p][h] += ra[e][h]; sDC[p][h] += rc[e][h]; }
      }
    }
    __syncthreads();
  }
  bool n0 = (tid == 0) || (sT[tid] != sT[tid - 1]);
  bool n1 = (sT[tid + 256] != sT[tid + 255]);
  unsigned long long m0 = __ballot(n0), m1 = __ballot(n1);
  unsigned long long below = (1ull << lane) - 1ull;
  int loc0 = __popcll(m0 & below), loc1 = __popcll(m1 & below);
  int* tot = sIdx;
  if (lane == 0) { tot[w] = __popcll(m0); tot[4 + w] = __popcll(m1); }
  __syncthreads();
  int t[8];
#pragma unroll
  for (int j = 0; j < 8; ++j) t[j] = tot[j];
  int nuniq = t[0] + t[1] + t[2] + t[3] + t[4] + t[5] + t[6] + t[7];
  int off0 = 0, off1 = t[0] + t[1] + t[2] + t[3];
  for (int j = 0; j < 4; ++j) {
    if (j < w) { off0 += t[j]; off1 += t[4 + j]; }
  }
  if (n0) {
    int u = off0 + loc0;
    a.wsT[u] = sT[tid];
    if (tid == 0) {
#pragma unroll
      for (int h = 0; h < 8; ++h) { a.wsA[h * 513] = sA0[h]; a.wsC[h * 513] = sC0[h]; }
    } else {
#pragma unroll
      for (int h = 0; h < 8; ++h) {
        a.wsA[h * 513 + u] = sA0[h] + sDA[tid - 1][h];
        a.wsC[h * 513 + u] = sC0[h] + sDC[tid - 1][h];
      }
    }
  }
  if (n1) {
    int u = off1 + loc1;
    a.wsT[u] = sT[tid + 256];
#pragma unroll
    for (int h = 0; h < 8; ++h) {
      a.wsA[h * 513 + u] = sA0[h] + sDA[tid + 255][h];
      a.wsC[h * 513 + u] = sC0[h] + sDC[tid + 255][h];
    }
  }
  if (tid == 0) {
#pragma unroll
    for (int h = 0; h < 8; ++h) {
      a.wsA[h * 513 + nuniq] = sA0[h] + sDA[511][h];
      a.wsC[h * 513 + nuniq] = sC0[h] + sDC[511][h];
    }
    *(int*)(a.wsT + 512) = nuniq;
  }
}

// ---------------- pre-pass: x fp32 -> bf16 (straight copy-convert) --------------------
__device__ void xconv_block(const float* __restrict__ x, unsigned short* __restrict__ xb, int j) {
  int tid = threadIdx.x;
  size_t base = (size_t)j * 16384;
#pragma unroll
  for (int it = 0; it < 8; ++it) {
    size_t idx = base + it * 2048 + tid * 8;
    float4 va = *(const float4*)(x + idx);
    float4 vb = *(const float4*)(x + idx + 4);
    *(uint4*)(xb + idx) = pack8(va, vb);
  }
}

// ---------------- pre-pass: W [k][n] fp32 -> W^T [n][k] bf16 via LDS tile -------------
__device__ void wtrans_block(const float* __restrict__ W, unsigned short* __restrict__ Wt,
                             int tile, char* smem) {
  float (*sW)[65] = (float (*)[65])smem;   // 64x65 fp32, padded
  int tid = threadIdx.x;
  int k0 = (tile >> 3) * 64, n0 = (tile & 7) * 64;
  int kr = tid >> 4, c4 = (tid & 15) * 4;
#pragma unroll
  for (int p = 0; p < 4; ++p) {
    int k = p * 16 + kr;
    float4 v = *(const float4*)(W + (size_t)(k0 + k) * 512 + n0 + c4);
    sW[k][c4] = v.x; sW[k][c4 + 1] = v.y; sW[k][c4 + 2] = v.z; sW[k][c4 + 3] = v.w;
  }
  __syncthreads();
  int n = tid >> 3, kk = (tid & 7) * 8;
#pragma unroll
  for (int p = 0; p < 2; ++p) {
    int nn = p * 32 + n;
    float4 va, vb;
    va.x = sW[kk][nn];     va.y = sW[kk + 1][nn]; va.z = sW[kk + 2][nn]; va.w = sW[kk + 3][nn];
    vb.x = sW[kk + 4][nn]; vb.y = sW[kk + 5][nn]; vb.z = sW[kk + 6][nn]; vb.w = sW[kk + 7][nn];
    *(uint4*)(Wt + (size_t)(n0 + nn) * 512 + k0 + kk) = pack8(va, vb);
  }
}

// ---------------- pure-bf16 MFMA GEMM 64x64 tile, global_load_lds staging -------------
// A: bf16 [M][512] row-major. Bt: bf16 [512 n][512 k] row-major (W^T).
// LDS linear dest + XOR-swizzled SOURCE addressing; reads use the same XOR (involution).
__device__ void gemm_bf(const unsigned short* __restrict__ A,
                        const unsigned short* __restrict__ Bt,
                        const float* __restrict__ bias,
                        void* out, int mode, int m0, int n0, char* smem) {
  char* sA = smem;           // 8192 B : [64 row][64 k] bf16, k-group^row&7 swizzle
  char* sB = smem + 8192;    // 8192 B : [64 n  ][64 k] bf16, same swizzle
  int tid = threadIdx.x, wave = tid >> 6, lane = tid & 63;
  int quad = lane >> 4, l16 = lane & 15;
  int lg = lane & 7, lr8 = lane >> 3;     // k-group / row-subindex for staging
  f32x4 acc[4] = {{0.f,0.f,0.f,0.f},{0.f,0.f,0.f,0.f},{0.f,0.f,0.f,0.f},{0.f,0.f,0.f,0.f}};
  int swr = l16 & 7;
  for (int kb = 0; kb < 512; kb += 64) {
    __syncthreads();
#pragma unroll
    for (int p = 0; p < 2; ++p) {
      int row = (p * 4 + wave) * 8 + lr8;          // row&7 == lr8
      int swz = (lg ^ lr8) << 3;                   // swizzled k-group (8 ushorts)
      gload16(A  + (size_t)(m0 + row) * 512 + kb + swz, sA + ((p * 4 + wave) << 10));
      gload16(Bt + (size_t)(n0 + row) * 512 + kb + swz, sB + ((p * 4 + wave) << 10));
    }
    __syncthreads();   // drains vmcnt(0): staged data visible
#pragma unroll
    for (int ks = 0; ks < 2; ++ks) {
      bf16x8 af = *(const bf16x8*)(sA + (wave * 16 + l16) * 128 + (((ks * 4 + quad) ^ swr) << 4));
#pragma unroll
      for (int nt = 0; nt < 4; ++nt) {
        bf16x8 bf = *(const bf16x8*)(sB + (nt * 16 + l16) * 128 + (((ks * 4 + quad) ^ swr) << 4));
        acc[nt] = __builtin_amdgcn_mfma_f32_16x16x32_bf16(af, bf, acc[nt], 0, 0, 0);
      }
    }
  }
  int mbase = m0 + wave * 16 + quad * 4;  // C row = quad*4+reg (m89-verified)
#pragma unroll
  for (int nt = 0; nt < 4; ++nt) {
    int n = n0 + nt * 16 + l16;
    float bv = bias[n];
#pragma unroll
    for (int r = 0; r < 4; ++r) {
      float v = acc[nt][r] + bv;
      int m = mbase + r;
      if (mode == 0) {
        int b = m >> 9, l = m & 511, hh = n >> 6, d = n & 63;
        ((unsigned short*)out)[(((size_t)(b * 8 + hh) * 512) + l) * 64 + d] = f2bf(v);
      } else if (mode == 1) {
        ((float*)out)[(size_t)m * 512 + n] = v;
      } else {
        int b = m >> 9, l = m & 511, hh = n >> 6, d = n & 63;
        ((unsigned short*)out)[(((size_t)(b * 8 + hh) * 64) + d) * 512 + l] = f2bf(v);
      }
    }
  }
}

// ---------------- fused edge-bias attention, deduped inline segment search ------------
__device__ void attn_block(const MegaArgs& a, int qt, int h, int b, char* smem) {
  float* sT  = (float*)smem;                                            // up to 2048
  float* sAh = (float*)(smem + 2048);                                   // up to 2052
  float* sCh = (float*)(smem + 4100);                                   // up to 2052
  unsigned short (*sP)[16][40] = (unsigned short (*)[16][40])(smem + 6160);  // 5120
  float (*sO)[4][16][16] = (float (*)[4][16][16])(smem + 11280);        // 16384
  float (*sM)[16] = (float (*)[16])(smem + 27664);                      // 256
  float (*sL)[16] = (float (*)[16])(smem + 27920);                      // 256
  const unsigned short* Qb = a.wsb + QB_OFF;
  const unsigned short* Kb = a.wsb + KB_OFF;
  const unsigned short* Vt = a.wsb + VT_OFF;
  int bh = b * 8 + h;
  int q0 = qt * 16;
  int tid = threadIdx.x, wave = tid >> 6, lane = tid & 63;
  int quad = lane >> 4, l16 = lane & 15;
  int nu = *(const int*)(a.wsT + 512);
  for (int i = tid; i < nu; i += 256) sT[i] = a.wsT[i];
  for (int i = tid; i <= nu; i += 256) { sAh[i] = a.wsA[h * 513 + i]; sCh[i] = a.wsC[h * 513 + i]; }
  const unsigned short* qp = Qb + ((size_t)bh * 512 + q0 + l16) * 64 + quad * 8;
  bf16x8 qf0 = *(const bf16x8*)qp;
  bf16x8 qf1 = *(const bf16x8*)(qp + 32);
  int key_base = wave * 128;
  f32x4 S[4][2];
#pragma unroll
  for (int kt = 0; kt < 4; ++kt) {
    int key0 = key_base + kt * 32;
#pragma unroll
    for (int half = 0; half < 2; ++half) {
      const unsigned short* kp = Kb + ((size_t)bh * 512 + key0 + half * 16 + l16) * 64 + quad * 8;
      bf16x8 kf0 = *(const bf16x8*)kp;
      bf16x8 kf1 = *(const bf16x8*)(kp + 32);
      f32x4 acc = {0.f, 0.f, 0.f, 0.f};
      acc = __builtin_amdgcn_mfma_f32_16x16x32_bf16(qf0, kf0, acc, 0, 0, 0);
      acc = __builtin_amdgcn_mfma_f32_16x16x32_bf16(qf1, kf1, acc, 0, 0, 0);
      S[kt][half] = acc;
    }
  }
  __syncthreads();  // sT/sAh/sCh ready (placed after MFMA issue to overlap)
#pragma unroll
  for (int kt = 0; kt < 4; ++kt)
#pragma unroll
    for (int half = 0; half < 2; ++half)
#pragma unroll
      for (int r = 0; r < 4; ++r) {
        int eidx = (b * 512 + q0 + quad * 4 + r) * 512 + key_base + kt * 32 + half * 16 + l16;
        float ev = a.eg[eidx];
        int lo = 0, hi = nu;
        while (lo < hi) {
          int mid = (lo + hi) >> 1;
          bool c = sT[mid] < ev;
          lo = c ? mid + 1 : lo;
          hi = c ? hi : mid;
        }
        S[kt][half][r] = S[kt][half][r] * 0.125f + sAh[lo] * ev + sCh[lo];
      }
  float m_w[4], l_w[4];
#pragma unroll
  for (int r = 0; r < 4; ++r) {
    float mx = -3.4e38f;
#pragma unroll
    for (int kt = 0; kt < 4; ++kt) { mx = fmaxf(mx, fmaxf(S[kt][0][r], S[kt][1][r])); }
    for (int off = 1; off < 16; off <<= 1) mx = fmaxf(mx, __shfl_xor(mx, off, 64));
    float s = 0.f;
#pragma unroll
    for (int kt = 0; kt < 4; ++kt)
#pragma unroll
      for (int half = 0; half < 2; ++half) {
        float p = exp2f((S[kt][half][r] - mx) * LOG2E);
        S[kt][half][r] = p; s += p;
      }
    for (int off = 1; off < 16; off <<= 1) s += __shfl_xor(s, off, 64);
    m_w[r] = mx; l_w[r] = s;
  }
  f32x4 Oacc[4] = {{0.f,0.f,0.f,0.f},{0.f,0.f,0.f,0.f},{0.f,0.f,0.f,0.f},{0.f,0.f,0.f,0.f}};
#pragma unroll
  for (int kt = 0; kt < 4; ++kt) {
    int key0 = key_base + kt * 32;
#pragma unroll
    for (int half = 0; half < 2; ++half)
#pragma unroll
      for (int r = 0; r < 4; ++r)
        sP[wave][quad * 4 + r][half * 16 + l16] = f2bf(S[kt][half][r]);
    __builtin_amdgcn_wave_barrier();
    bf16x8 pf = *(const bf16x8*)&sP[wave][l16][quad * 8];
    __builtin_amdgcn_wave_barrier();
#pragma unroll
    for (int nt = 0; nt < 4; ++nt) {
      bf16x8 vf = *(const bf16x8*)(Vt + ((size_t)bh * 64 + nt * 16 + l16) * 512 + key0 + quad * 8);
      Oacc[nt] = __builtin_amdgcn_mfma_f32_16x16x32_bf16(pf, vf, Oacc[nt], 0, 0, 0);
    }
  }
  if (l16 == 0) {
#pragma unroll
    for (int r = 0; r < 4; ++r) { sM[wave][quad * 4 + r] = m_w[r]; sL[wave][quad * 4 + r] = l_w[r]; }
  }
#pragma unroll
  for (int nt = 0; nt < 4; ++nt)
#pragma unroll
    for (int r = 0; r < 4; ++r)
      sO[wave][nt][quad * 4 + r][l16] = Oacc[nt][r];
  __syncthreads();
#pragma unroll
  for (int r = 0; r < 4; ++r) {
    int row = quad * 4 + r;
    float M = fmaxf(fmaxf(sM[0][row], sM[1][row]), fmaxf(sM[2][row], sM[3][row]));
    float L = 0.f, Ov = 0.f;
#pragma unroll
    for (int wv = 0; wv < 4; ++wv) {
      float f = exp2f((sM[wv][row] - M) * LOG2E);
      L += f * sL[wv][row];
      Ov += f * sO[wv][wave][row][l16];
    }
    float v = Ov / L;
    (a.wsb + AO_OFF)[((size_t)(b * 512 + q0 + row)) * 512 + h * 64 + wave * 16 + l16] = f2bf(v);
  }
}

// ---------------- launch 1: prep + x convert + W transpose-convert --------------------
__global__ __launch_bounds__(256) void kprep(MegaArgs a) {
  __shared__ __align__(16) char smem[36928];
  int blk = blockIdx.x;
  if (blk == 0) { prep_block(a, smem); return; }
  if (blk <= 96) {
    int g = blk - 1, z = g >> 5, j = g & 31;
    const float* x = (z == 0) ? a.xq : (z == 1) ? a.xk : a.xv;
    xconv_block(x, a.wsb + XB_OFF + (size_t)z * 524288, j);
    return;
  }
  int g = blk - 97, z = g >> 6, t = g & 63;
  const float* W = (z == 0) ? a.wq : (z == 1) ? a.wk : (z == 2) ? a.wv : a.wo;
  wtrans_block(W, a.wsb + WT_OFF + (size_t)z * 262144, t, smem);
}

// ---------------- launch 2: QKV GEMMs, all-bf16 ---------------------------------------
__global__ __launch_bounds__(256) void kqkv(MegaArgs a) {
  __shared__ __align__(16) char smem[16384];
  int blk = blockIdx.x;
  int z = blk >> 7, rem = blk & 127;
  const unsigned short* A  = a.wsb + XB_OFF + (size_t)z * 524288;
  const unsigned short* Bt = a.wsb + WT_OFF + (size_t)z * 262144;
  const float* bias = (z == 0) ? a.bq : (z == 1) ? a.bk : a.bv;
  void* outp = (void*)(a.wsb + ((z == 0) ? QB_OFF : (z == 1) ? KB_OFF : VT_OFF));
  gemm_bf(A, Bt, bias, outp, (z == 2) ? 2 : 0, (rem & 15) * 64, (rem >> 4) * 64, smem);
}

// ---------------- launch 3: attention (h-fastest for eg L2 reuse) ---------------------
__global__ __launch_bounds__(256) void kattn(MegaArgs a) {
  __shared__ __align__(16) char smem[28176];
  int blk = blockIdx.x;
  attn_block(a, (blk >> 3) & 31, blk & 7, blk >> 8, smem);
}

// ---------------- launch 4: output GEMM, all-bf16 -------------------------------------
__global__ __launch_bounds__(256) void kout(MegaArgs a) {
  __shared__ __align__(16) char smem[16384];
  gemm_bf(a.wsb + AO_OFF, a.wsb + WT_OFF + (size_t)3 * 262144, a.bo, (void*)a.out, 1,
          (blockIdx.x & 15) * 64, (blockIdx.x >> 4) * 64, smem);
}

extern "C" void kernel_launch(void* const* d_in, const int* in_sizes, int n_in,
                              void* d_out, int out_size, void* d_ws, size_t ws_size,
                              hipStream_t stream) {
  MegaArgs a;
  a.xq  = (const float*)d_in[0];
  a.xk  = (const float*)d_in[1];
  a.xv  = (const float*)d_in[2];
  a.eg  = (const float*)d_in[3];
  a.wq  = (const float*)d_in[4];
  a.bq  = (const float*)d_in[5];
  a.wk  = (const float*)d_in[6];
  a.bk  = (const float*)d_in[7];
  a.wv  = (const float*)d_in[8];
  a.bv  = (const float*)d_in[9];
  a.wo  = (const float*)d_in[10];
  a.bo  = (const float*)d_in[11];
  a.w1  = (const float*)d_in[12];
  a.b1  = (const float*)d_in[13];
  a.we2 = (const float*)d_in[14];
  a.be2 = (const float*)d_in[15];
  a.out = (float*)d_out;
  a.wsb = (unsigned short*)d_ws;
  a.wsT = (float*)((char*)d_ws + T_B);
  a.wsA = (float*)((char*)d_ws + A_B);
  a.wsC = (float*)((char*)d_ws + C_B);

  kprep<<<353, 256, 0, stream>>>(a);
  kqkv<<<384, 256, 0, stream>>>(a);
  kattn<<<512, 256, 0, stream>>>(a);
  kout<<<128, 256, 0, stream>>>(a);
}